// Round 7
// baseline (314.447 us; speedup 1.0000x reference)
//
#include <hip/hip_runtime.h>
#include <hip/hip_bf16.h>

#define IN_CH 128
#define HID   64
#define N_REL 8
// GEMM K layout: [0,1024) = 8 relation x-sums, [1024,1152) = self x,
// [1152,1160) = relation counts (bias via counts), [1160,1184) = zero pad.
#define KTOT  1184
#define KSTEP 37            // 1184 / 32
#define SROW  596           // S row stride in u32 (1192 ch) — bank-conflict-free

using bf16x8 = __attribute__((ext_vector_type(8))) short;  // 8 bf16 (4 VGPRs)
using f32x4  = __attribute__((ext_vector_type(4))) float;

__device__ __forceinline__ short f2bf(float f) {          // RNE float->bf16
    unsigned int u = __float_as_uint(f);
    u += 0x7fffu + ((u >> 16) & 1u);
    return (short)(u >> 16);
}

// ---------------------------------------------------------------------------
// x2bf: x [N,128] fp32 -> xb [N,128] bf16. One thread = 8 elements.
// ---------------------------------------------------------------------------
__global__ __launch_bounds__(256) void x2bf_kernel(
    const float* __restrict__ x, unsigned short* __restrict__ xb, int total8)
{
    int i = blockIdx.x * 256 + threadIdx.x;
    if (i >= total8) return;
    const float* p = x + (size_t)i * 8;
    float4 a = *(const float4*)p;
    float4 b = *(const float4*)(p + 4);
    bf16x8 o;
    o[0]=f2bf(a.x); o[1]=f2bf(a.y); o[2]=f2bf(a.z); o[3]=f2bf(a.w);
    o[4]=f2bf(b.x); o[5]=f2bf(b.y); o[6]=f2bf(b.z); o[7]=f2bf(b.w);
    *(bf16x8*)(xb + (size_t)i * 8) = o;
}

// ---------------------------------------------------------------------------
// pack_w2: Wcat [64 h][1184 k] -> bf16 MFMA A-fragment order.
//   Wcat[h][k] = k<1024: W_rel[k/128][h][k%128]
//                1024<=k<1152: W_self[h][k-1024]
//                1152<=k<1160: b_rel[k-1152][h]
//                else 0
//   wpk[((s2*4 + t)*64 + lane)*8 + j] = Wcat[t*16+(lane&15)][s2*32+(lane>>4)*8+j]
// ---------------------------------------------------------------------------
__global__ __launch_bounds__(256) void pack_w2_kernel(
    const float* __restrict__ W_rel, const float* __restrict__ W_self,
    const float* __restrict__ b_rel, unsigned short* __restrict__ wpk)
{
    int gid = blockIdx.x * 256 + threadIdx.x;     // 37*4*64 = 9472
    if (gid >= KSTEP * 4 * 64) return;
    int s2   = gid >> 8;
    int t    = (gid >> 6) & 3;
    int lane = gid & 63;
    int h    = t * 16 + (lane & 15);
    int kb   = s2 * 32 + (lane >> 4) * 8;
    bf16x8 o;
    #pragma unroll
    for (int j = 0; j < 8; ++j) {
        int k = kb + j;
        float v;
        if (k < 1024)       v = W_rel[(size_t)(k >> 7) * HID * IN_CH + (size_t)h * IN_CH + (k & 127)];
        else if (k < 1152)  v = W_self[(size_t)h * IN_CH + (k - 1024)];
        else if (k < 1160)  v = b_rel[(k - 1152) * HID + h];
        else                v = 0.f;
        o[j] = f2bf(v);
    }
    *(bf16x8*)(wpk + (size_t)gid * 8) = o;
}

// ---------------------------------------------------------------------------
// CSR build keyed by (dst*8 + type): histogram -> 2-level exclusive scan ->
// fill (payload = src only; type implied by segment).
// ---------------------------------------------------------------------------
__global__ __launch_bounds__(256) void hist_kernel(
    const int* __restrict__ edge_index, const int* __restrict__ edge_type,
    int* __restrict__ cnt, int E)
{
    int e = blockIdx.x * 256 + threadIdx.x;
    if (e < E) atomicAdd(&cnt[edge_index[E + e] * N_REL + edge_type[e]], 1);
}

#define SCAN_E 1024   // elements per scan block (256 threads x 4)

__global__ __launch_bounds__(256) void scan_blocksum_kernel(
    const int* __restrict__ cnt, int* __restrict__ bsum, int M)
{
    __shared__ int s[256];
    int tid = threadIdx.x;
    int base = blockIdx.x * SCAN_E + tid * 4;
    int v = 0;
    #pragma unroll
    for (int j = 0; j < 4; ++j)
        if (base + j < M) v += cnt[base + j];
    s[tid] = v; __syncthreads();
    for (int off = 128; off > 0; off >>= 1) {
        if (tid < off) s[tid] += s[tid + off];
        __syncthreads();
    }
    if (tid == 0) bsum[blockIdx.x] = s[0];
}

__global__ __launch_bounds__(256) void scan_partials_kernel(
    int* __restrict__ bsum, int NB)   // NB <= 1024
{
    __shared__ int s[256];
    int tid = threadIdx.x;
    int base = tid * 4;
    int v[4]; int sum = 0;
    #pragma unroll
    for (int j = 0; j < 4; ++j) {
        v[j] = (base + j < NB) ? bsum[base + j] : 0;
        sum += v[j];
    }
    s[tid] = sum; __syncthreads();
    for (int off = 1; off < 256; off <<= 1) {
        int t = (tid >= off) ? s[tid - off] : 0;
        __syncthreads();
        s[tid] += t;
        __syncthreads();
    }
    int run = s[tid] - sum;   // exclusive prefix
    #pragma unroll
    for (int j = 0; j < 4; ++j) {
        if (base + j < NB) { int t = v[j]; bsum[base + j] = run; run += t; }
    }
}

__global__ __launch_bounds__(256) void scan_write_kernel(
    const int* __restrict__ cnt, const int* __restrict__ bsumx,
    int* __restrict__ offsets, int* __restrict__ cursor, int M)
{
    __shared__ int s[256];
    int tid = threadIdx.x;
    int base = blockIdx.x * SCAN_E + tid * 4;
    int v[4]; int sum = 0;
    #pragma unroll
    for (int j = 0; j < 4; ++j) {
        v[j] = (base + j < M) ? cnt[base + j] : 0;
        sum += v[j];
    }
    s[tid] = sum; __syncthreads();
    for (int off = 1; off < 256; off <<= 1) {
        int w = (tid >= off) ? s[tid - off] : 0;
        __syncthreads();
        s[tid] += w;
        __syncthreads();
    }
    int running = bsumx[blockIdx.x] + s[tid] - sum;
    #pragma unroll
    for (int j = 0; j < 4; ++j) {
        int i = base + j;
        if (i < M) {
            offsets[i] = running;
            cursor[i]  = running;
            running += v[j];
            if (i == M - 1) offsets[M] = running;   // = E
        }
    }
}

__global__ __launch_bounds__(256) void fill_csr_kernel(
    const int* __restrict__ edge_index, const int* __restrict__ edge_type,
    int* __restrict__ cursor, unsigned int* __restrict__ csr, int E)
{
    int e = blockIdx.x * 256 + threadIdx.x;
    if (e >= E) return;
    int key = edge_index[E + e] * N_REL + edge_type[e];
    int pos = atomicAdd(&cursor[key], 1);
    csr[pos] = (unsigned int)edge_index[e];    // src
}

// ---------------------------------------------------------------------------
// fused: per 16-node block:
//  1. gather: S[node][r*128..] = bf16(Σ_{e:type r} x_src); self row; counts.
//  2. MFMA GEMM: D[node][h] = Σ_k Wcat[h][k]·S[node][k]  (K split over 4 waves)
//  3. epilogue: out[n] = W_out·relu(D + b_self) + b_out
// ---------------------------------------------------------------------------
__global__ __launch_bounds__(256) void rgcn_fused_kernel(
    const unsigned int* __restrict__ xbu,   // [N*64] u32 = bf16 pairs
    const unsigned short* __restrict__ wpk, // packed Wcat fragments
    const int* __restrict__ off2,           // [8N+1]
    const unsigned int* __restrict__ csr,   // [E] src
    const float* __restrict__ b_self,       // [64]
    const float* __restrict__ W_out,        // [64]
    const float* __restrict__ b_out,        // [1]
    float* __restrict__ out,                // [N]
    int N)
{
    __shared__ unsigned int S[16 * SROW];   // 38,144 B
    const int tid  = threadIdx.x;
    const int wave = tid >> 6;
    const int lane = tid & 63;
    const int l16  = lane & 15;
    const int quad = lane >> 4;
    const int nb   = blockIdx.x * 16;

    // ---- zero S ----
    for (int i = tid; i < 16 * SROW; i += 256) S[i] = 0;
    __syncthreads();

    // ---- gather phase: wave handles 4 nodes ----
    for (int nd4 = 0; nd4 < 4; ++nd4) {
        const int node  = wave * 4 + nd4;
        const int gnode = nb + node;
        // self channels [1024,1152): u32 idx 512+lane
        S[node * SROW + 512 + lane] = xbu[(size_t)gnode * 64 + lane];

        const int g8 = gnode * N_REL;
        int bv = (lane < 9) ? off2[g8 + lane] : 0;   // 9 segment bounds
        const int base   = __shfl(bv, 0, 64);
        const int endall = __shfl(bv, 8, 64);
        const int deg    = endall - base;
        unsigned int ev = (lane < deg) ? csr[base + lane] : 0u;  // edge cache
        unsigned short* Srow16 = (unsigned short*)&S[node * SROW];

        int e0 = base;
        for (int r = 0; r < 8; ++r) {
            const int e1 = __shfl(bv, r + 1, 64);
            if (e1 > e0) {
                float s0 = 0.f, s1 = 0.f;
                for (int e = e0; e < e1; ++e) {
                    int idx = e - base;                      // wave-uniform
                    unsigned int v = (idx < 64) ? (unsigned int)__shfl((int)ev, idx, 64)
                                                : csr[e];
                    unsigned int w = xbu[(size_t)v * 64 + lane];
                    s0 += __uint_as_float(w << 16);
                    s1 += __uint_as_float(w & 0xffff0000u);
                }
                unsigned int p = ((unsigned int)(unsigned short)f2bf(s1) << 16)
                               | (unsigned int)(unsigned short)f2bf(s0);
                S[node * SROW + r * 64 + lane] = p;
                if (lane == 0)   // count channel (bias via GEMM)
                    Srow16[1152 + r] = (unsigned short)f2bf((float)(e1 - e0));
            }
            e0 = e1;
        }
    }
    __syncthreads();

    // ---- MFMA phase: wave w covers k-steps w, w+4, ... ----
    f32x4 acc[4] = {{0.f,0.f,0.f,0.f},{0.f,0.f,0.f,0.f},
                    {0.f,0.f,0.f,0.f},{0.f,0.f,0.f,0.f}};
    const bf16x8* wv = (const bf16x8*)wpk;
    for (int s2 = wave; s2 < KSTEP; s2 += 4) {
        bf16x8 a[4];
        #pragma unroll
        for (int t = 0; t < 4; ++t)
            a[t] = wv[(size_t)((s2 * 4 + t) * 64) + lane];
        bf16x8 b = *(const bf16x8*)&S[l16 * SROW + s2 * 16 + quad * 4];
        #pragma unroll
        for (int t = 0; t < 4; ++t)
            acc[t] = __builtin_amdgcn_mfma_f32_16x16x32_bf16(a[t], b, acc[t], 0, 0, 0);
    }
    __syncthreads();   // everyone done reading S -> reuse as partial buffer

    // ---- partial store: P[wave][node][h], node row stride 68 f32 ----
    float* Pf = (float*)S;
    #pragma unroll
    for (int t = 0; t < 4; ++t)
        *(f32x4*)&Pf[wave * 1088 + l16 * 68 + t * 16 + quad * 4] = acc[t];
    __syncthreads();

    // ---- reduce over waves + relu + W_out partial dot ----
    {
        const int node = tid & 15, hg = tid >> 4;   // hg in [0,16): 4 h each
        float4 bs = *(const float4*)(b_self + hg * 4);
        float4 wo = *(const float4*)(W_out + hg * 4);
        float part = 0.f;
        #pragma unroll
        for (int j = 0; j < 4; ++j) {
            float v = 0.f;
            #pragma unroll
            for (int w2 = 0; w2 < 4; ++w2)
                v += Pf[w2 * 1088 + node * 68 + hg * 4 + j];
            v += (&bs.x)[j];
            v = fmaxf(v, 0.f);
            part += v * (&wo.x)[j];
        }
        Pf[4608 + hg * 16 + node] = part;   // region disjoint from P (<4352)
    }
    __syncthreads();
    if (tid < 16) {
        float sum = 0.f;
        #pragma unroll
        for (int hg = 0; hg < 16; ++hg) sum += Pf[4608 + hg * 16 + tid];
        out[nb + tid] = sum + b_out[0];
    }
}

extern "C" void kernel_launch(void* const* d_in, const int* in_sizes, int n_in,
                              void* d_out, int out_size, void* d_ws, size_t ws_size,
                              hipStream_t stream)
{
    const float* x          = (const float*)d_in[0];
    const int*   edge_index = (const int*)  d_in[1];
    const int*   edge_type  = (const int*)  d_in[2];
    const float* W_rel      = (const float*)d_in[3];
    const float* b_rel      = (const float*)d_in[4];
    const float* W_self     = (const float*)d_in[5];
    const float* b_self     = (const float*)d_in[6];
    const float* W_out      = (const float*)d_in[7];
    const float* b_out      = (const float*)d_in[8];
    float* out = (float*)d_out;

    const int N = in_sizes[0] / IN_CH;   // 100000 (multiple of 16)
    const int E = in_sizes[2];           // 600000
    const int M = N * N_REL;             // 800000 (dst,type) keys

    // workspace layout (256 B aligned)
    char* w = (char*)d_ws;
    unsigned short* xb = (unsigned short*)w;   // [N,128] bf16, 25.6 MB
    w += (size_t)N * IN_CH * 2;
    unsigned short* wpk = (unsigned short*)w;  // 151.6 KB
    w += (size_t)KSTEP * 4 * 64 * 8 * 2;
    int* cnt     = (int*)w;  w += (size_t)M * 4;
    int* off2    = (int*)w;  w += (size_t)(M + 1) * 4 + 252;
    int* cursor  = (int*)w;  w += (size_t)M * 4;
    int* bsum    = (int*)w;  w += 1024 * 4;
    unsigned int* csr = (unsigned int*)w;      // [E] u32, 2.4 MB

    const int NB = (M + SCAN_E - 1) / SCAN_E;  // 782 (<=1024 required)

    // 0) one-shot preps
    pack_w2_kernel<<<KSTEP, 256, 0, stream>>>(W_rel, W_self, b_rel, wpk);
    x2bf_kernel<<<(N * IN_CH / 8 + 255) / 256, 256, 0, stream>>>(
        x, xb, N * IN_CH / 8);

    // 1) CSR build keyed by (dst, type)
    hipMemsetAsync(cnt, 0, (size_t)M * 4, stream);
    hist_kernel<<<(E + 255) / 256, 256, 0, stream>>>(edge_index, edge_type, cnt, E);
    scan_blocksum_kernel<<<NB, 256, 0, stream>>>(cnt, bsum, M);
    scan_partials_kernel<<<1, 256, 0, stream>>>(bsum, NB);
    scan_write_kernel<<<NB, 256, 0, stream>>>(cnt, bsum, off2, cursor, M);
    fill_csr_kernel<<<(E + 255) / 256, 256, 0, stream>>>(edge_index, edge_type,
                                                         cursor, csr, E);

    // 2) fused gather-sum + GEMM + relu + output projection
    rgcn_fused_kernel<<<N / 16, 256, 0, stream>>>(
        (const unsigned int*)xb, wpk, off2, csr,
        b_self, W_out, b_out, out, N);
}

// Round 8
// 298.149 us; speedup vs baseline: 1.0547x; 1.0547x over previous
//
#include <hip/hip_runtime.h>
#include <hip/hip_bf16.h>

#define IN_CH 128
#define HID   64
#define N_REL 8
// GEMM K layout: [0,1024) = 8 relation x-sums, [1024,1152) = self x.
#define KTOT  1152
#define KSTEP 36            // 1152 / 32
#define SROW2 580           // Sb row stride in u32 (16B-aligned, conflict-light)

using bf16x8 = __attribute__((ext_vector_type(8))) short;  // 8 bf16 (4 VGPRs)
using f32x4  = __attribute__((ext_vector_type(4))) float;

__device__ __forceinline__ short f2bf(float f) {          // RNE float->bf16
    unsigned int u = __float_as_uint(f);
    u += 0x7fffu + ((u >> 16) & 1u);
    return (short)(u >> 16);
}

// ---------------------------------------------------------------------------
// prep: fused one-shot preparations, branched by block range:
//   [0, nb_xb)            : x fp32 -> xb bf16 (8 elems/thread)
//   [nb_xb, nb_xb+36)     : pack Wcat [64][1152] into MFMA A-fragment order
//   [nb_xb+36, ...)       : zero cnt[M]
// ---------------------------------------------------------------------------
__global__ __launch_bounds__(256) void prep_kernel(
    const float* __restrict__ x, unsigned short* __restrict__ xb, int total8,
    const float* __restrict__ W_rel, const float* __restrict__ W_self,
    unsigned short* __restrict__ wpk,
    int* __restrict__ cnt, int M, int nb_xb)
{
    const int b = blockIdx.x, tid = threadIdx.x;
    if (b < nb_xb) {
        int i = b * 256 + tid;
        if (i >= total8) return;
        const float* p = x + (size_t)i * 8;
        float4 a = *(const float4*)p;
        float4 c = *(const float4*)(p + 4);
        bf16x8 o;
        o[0]=f2bf(a.x); o[1]=f2bf(a.y); o[2]=f2bf(a.z); o[3]=f2bf(a.w);
        o[4]=f2bf(c.x); o[5]=f2bf(c.y); o[6]=f2bf(c.z); o[7]=f2bf(c.w);
        *(bf16x8*)(xb + (size_t)i * 8) = o;
    } else if (b < nb_xb + 36) {
        int gid = (b - nb_xb) * 256 + tid;       // < 9216
        int s2   = gid >> 8;
        int t    = (gid >> 6) & 3;
        int lane = gid & 63;
        int h    = t * 16 + (lane & 15);
        int kb   = s2 * 32 + (lane >> 4) * 8;
        bf16x8 o;
        #pragma unroll
        for (int j = 0; j < 8; ++j) {
            int k = kb + j;
            float v = (k < 1024)
                ? W_rel[(size_t)(k >> 7) * HID * IN_CH + (size_t)h * IN_CH + (k & 127)]
                : W_self[(size_t)h * IN_CH + (k - 1024)];
            o[j] = f2bf(v);
        }
        *(bf16x8*)(wpk + (size_t)gid * 8) = o;
    } else {
        int idx = (b - nb_xb - 36) * 1024 + tid * 4;
        if (idx < M) *(int4*)(cnt + idx) = make_int4(0, 0, 0, 0);
    }
}

// ---------------------------------------------------------------------------
// CSR build keyed by (dst*8 + type); payload = src | (type<<17).
// ---------------------------------------------------------------------------
__global__ __launch_bounds__(256) void hist_kernel(
    const int* __restrict__ edge_index, const int* __restrict__ edge_type,
    int* __restrict__ cnt, int E)
{
    int e = blockIdx.x * 256 + threadIdx.x;
    if (e < E) atomicAdd(&cnt[edge_index[E + e] * N_REL + edge_type[e]], 1);
}

#define SCAN_E 1024   // elements per scan block (256 threads x 4)

__global__ __launch_bounds__(256) void scan_blocksum_kernel(
    const int* __restrict__ cnt, int* __restrict__ bsum, int M)
{
    __shared__ int s[256];
    int tid = threadIdx.x;
    int base = blockIdx.x * SCAN_E + tid * 4;
    int v = 0;
    #pragma unroll
    for (int j = 0; j < 4; ++j)
        if (base + j < M) v += cnt[base + j];
    s[tid] = v; __syncthreads();
    for (int off = 128; off > 0; off >>= 1) {
        if (tid < off) s[tid] += s[tid + off];
        __syncthreads();
    }
    if (tid == 0) bsum[blockIdx.x] = s[0];
}

__global__ __launch_bounds__(256) void scan_partials_kernel(
    int* __restrict__ bsum, int NB)   // NB <= 1024
{
    __shared__ int s[256];
    int tid = threadIdx.x;
    int base = tid * 4;
    int v[4]; int sum = 0;
    #pragma unroll
    for (int j = 0; j < 4; ++j) {
        v[j] = (base + j < NB) ? bsum[base + j] : 0;
        sum += v[j];
    }
    s[tid] = sum; __syncthreads();
    for (int off = 1; off < 256; off <<= 1) {
        int t = (tid >= off) ? s[tid - off] : 0;
        __syncthreads();
        s[tid] += t;
        __syncthreads();
    }
    int run = s[tid] - sum;   // exclusive prefix
    #pragma unroll
    for (int j = 0; j < 4; ++j)
        if (base + j < NB) { int t = v[j]; bsum[base + j] = run; run += t; }
}

__global__ __launch_bounds__(256) void scan_write_kernel(
    const int* __restrict__ cnt, const int* __restrict__ bsumx,
    int* __restrict__ offsets, int* __restrict__ cursor, int M)
{
    __shared__ int s[256];
    int tid = threadIdx.x;
    int base = blockIdx.x * SCAN_E + tid * 4;
    int v[4]; int sum = 0;
    #pragma unroll
    for (int j = 0; j < 4; ++j) {
        v[j] = (base + j < M) ? cnt[base + j] : 0;
        sum += v[j];
    }
    s[tid] = sum; __syncthreads();
    for (int off = 1; off < 256; off <<= 1) {
        int w = (tid >= off) ? s[tid - off] : 0;
        __syncthreads();
        s[tid] += w;
        __syncthreads();
    }
    int running = bsumx[blockIdx.x] + s[tid] - sum;
    #pragma unroll
    for (int j = 0; j < 4; ++j) {
        int i = base + j;
        if (i < M) {
            offsets[i] = running;
            cursor[i]  = running;
            running += v[j];
            if (i == M - 1) offsets[M] = running;   // = E
        }
    }
}

__global__ __launch_bounds__(256) void fill_csr_kernel(
    const int* __restrict__ edge_index, const int* __restrict__ edge_type,
    int* __restrict__ cursor, unsigned int* __restrict__ csr, int E)
{
    int e = blockIdx.x * 256 + threadIdx.x;
    if (e >= E) return;
    unsigned int t = (unsigned int)edge_type[e];
    int key = edge_index[E + e] * N_REL + (int)t;
    int pos = atomicAdd(&cursor[key], 1);
    csr[pos] = (unsigned int)edge_index[e] | (t << 17);   // src | type
}

// ---------------------------------------------------------------------------
// fused: block = 1024 threads = 16 waves = 16 dst nodes.
//  gather: wave w sums x_src per relation for node nb+w (edge list prefetched
//          into registers, 8 independent gathers in flight per chunk),
//          flushes bf16 pairs to LDS Sb[node][k]; counts to cntS.
//  GEMM:   waves 0-3 K-split (9 steps each): D = Wcat · Sb^T via MFMA.
//  epilogue: D + b_self + sum_r cnt_r*b_rel[r] (fp32), relu, dot W_out -> out.
// ---------------------------------------------------------------------------
__global__ __launch_bounds__(1024, 8) void rgcn_fused_kernel(
    const unsigned int* __restrict__ xbu,   // [N*64] u32 = bf16 channel pairs
    const unsigned short* __restrict__ wpk, // packed Wcat fragments
    const int* __restrict__ off2,           // [8N+1]
    const unsigned int* __restrict__ csr,   // [E] src | type<<17
    const float* __restrict__ b_rel,        // [8,64]
    const float* __restrict__ b_self,       // [64]
    const float* __restrict__ W_out,        // [64]
    const float* __restrict__ b_out,        // [1]
    float* __restrict__ out,                // [N]
    int N)
{
    __shared__ unsigned int Sb[16 * SROW2];   // 37,120 B
    __shared__ unsigned int cntS[16 * 8];     // 512 B
    const int tid  = threadIdx.x;
    const int wave = tid >> 6;                // 0..15 = local node
    const int lane = tid & 63;
    const int l16  = lane & 15;
    const int quad = lane >> 4;
    const int nb   = blockIdx.x * 16;

    for (int i = tid; i < 16 * SROW2; i += 1024) Sb[i] = 0;
    if (tid < 128) cntS[tid] = 0;
    __syncthreads();

    // ---- gather: wave handles node nb+wave ----
    {
        const int node  = wave;
        const int gnode = nb + node;
        // self channels [1024,1152) -> u32 idx 512+lane
        Sb[node * SROW2 + 512 + lane] = xbu[(size_t)gnode * 64 + lane];

        int bv = (lane < 9) ? off2[gnode * N_REL + lane] : 0;
        const int base = __shfl(bv, 0, 64);
        const int deg  = __shfl(bv, 8, 64) - base;
        unsigned int ev = (lane < deg) ? csr[base + lane] : 0u;  // deg<=64 fast path

        float s0 = 0.f, s1 = 0.f;
        int cur_r = -1, ecnt = 0;
        const int nch = (deg + 7) >> 3;
        for (int c = 0; c < nch; ++c) {
            unsigned int vv[8], uu[8];
            #pragma unroll
            for (int i = 0; i < 8; ++i) {
                const int idx = c * 8 + i;
                unsigned int v;
                if (idx < 64) v = (unsigned int)__shfl((int)ev, idx, 64);
                else          v = (idx < deg) ? csr[base + idx] : 0u;  // rare
                vv[i] = v;
                uu[i] = (idx < deg) ? xbu[(size_t)(v & 0x1FFFFu) * 64 + lane] : 0u;
            }
            #pragma unroll
            for (int i = 0; i < 8; ++i) {
                const int idx = c * 8 + i;
                if (idx < deg) {
                    const int r = (int)(vv[i] >> 17);
                    if (r != cur_r) {               // wave-uniform branch
                        if (cur_r >= 0) {
                            unsigned int p =
                                ((unsigned int)(unsigned short)f2bf(s1) << 16)
                              | (unsigned int)(unsigned short)f2bf(s0);
                            Sb[node * SROW2 + cur_r * 64 + lane] = p;
                            if (lane == 0) cntS[node * 8 + cur_r] = (unsigned int)ecnt;
                        }
                        cur_r = r; s0 = 0.f; s1 = 0.f; ecnt = 0;
                    }
                    const unsigned int w = uu[i];
                    s0 += __uint_as_float(w << 16);
                    s1 += __uint_as_float(w & 0xffff0000u);
                    ++ecnt;
                }
            }
        }
        if (cur_r >= 0) {
            unsigned int p = ((unsigned int)(unsigned short)f2bf(s1) << 16)
                           | (unsigned int)(unsigned short)f2bf(s0);
            Sb[node * SROW2 + cur_r * 64 + lane] = p;
            if (lane == 0) cntS[node * 8 + cur_r] = (unsigned int)ecnt;
        }
    }
    __syncthreads();

    // ---- GEMM: waves 0-3, wave w covers k-steps w*9 .. w*9+8 ----
    f32x4 acc[4] = {{0.f,0.f,0.f,0.f},{0.f,0.f,0.f,0.f},
                    {0.f,0.f,0.f,0.f},{0.f,0.f,0.f,0.f}};
    if (wave < 4) {
        const bf16x8* wv = (const bf16x8*)wpk;
        #pragma unroll
        for (int q = 0; q < 9; ++q) {
            const int s2 = wave * 9 + q;
            bf16x8 a[4];
            #pragma unroll
            for (int t = 0; t < 4; ++t)
                a[t] = wv[(size_t)((s2 * 4 + t) * 64) + lane];
            bf16x8 bfrag = *(const bf16x8*)&Sb[l16 * SROW2 + s2 * 16 + quad * 4];
            #pragma unroll
            for (int t = 0; t < 4; ++t)
                acc[t] = __builtin_amdgcn_mfma_f32_16x16x32_bf16(
                    a[t], bfrag, acc[t], 0, 0, 0);
        }
    }
    __syncthreads();   // all GEMM reads of Sb complete

    // ---- partials into LDS (reuse Sb): P[w][node][h], node stride 68 ----
    float* Pf = (float*)Sb;
    if (wave < 4) {
        #pragma unroll
        for (int t = 0; t < 4; ++t)
            *(f32x4*)&Pf[wave * 1100 + l16 * 68 + t * 16 + quad * 4] = acc[t];
    }
    __syncthreads();

    // ---- epilogue: 256 threads -> (node, h-group of 4) ----
    if (tid < 256) {
        const int node = tid & 15, hg = tid >> 4;
        float4 bs = *(const float4*)(b_self + hg * 4);
        float4 wo = *(const float4*)(W_out + hg * 4);
        float cb[4] = {0.f, 0.f, 0.f, 0.f};
        #pragma unroll
        for (int r = 0; r < 8; ++r) {
            float cf = (float)cntS[node * 8 + r];
            if (cf != 0.f) {
                float4 br = *(const float4*)(b_rel + r * HID + hg * 4);
                cb[0] += cf * br.x; cb[1] += cf * br.y;
                cb[2] += cf * br.z; cb[3] += cf * br.w;
            }
        }
        float part = 0.f;
        #pragma unroll
        for (int j = 0; j < 4; ++j) {
            float v = Pf[0 * 1100 + node * 68 + hg * 4 + j]
                    + Pf[1 * 1100 + node * 68 + hg * 4 + j]
                    + Pf[2 * 1100 + node * 68 + hg * 4 + j]
                    + Pf[3 * 1100 + node * 68 + hg * 4 + j];
            v += (&bs.x)[j] + cb[j];
            v = fmaxf(v, 0.f);
            part += v * (&wo.x)[j];
        }
        Pf[4608 + hg * 16 + node] = part;   // disjoint from P (< 4384)
    }
    __syncthreads();
    if (tid < 16) {
        float sum = 0.f;
        #pragma unroll
        for (int hg = 0; hg < 16; ++hg) sum += Pf[4608 + hg * 16 + tid];
        out[nb + tid] = sum + b_out[0];
    }
}

extern "C" void kernel_launch(void* const* d_in, const int* in_sizes, int n_in,
                              void* d_out, int out_size, void* d_ws, size_t ws_size,
                              hipStream_t stream)
{
    const float* x          = (const float*)d_in[0];
    const int*   edge_index = (const int*)  d_in[1];
    const int*   edge_type  = (const int*)  d_in[2];
    const float* W_rel      = (const float*)d_in[3];
    const float* b_rel      = (const float*)d_in[4];
    const float* W_self     = (const float*)d_in[5];
    const float* b_self     = (const float*)d_in[6];
    const float* W_out      = (const float*)d_in[7];
    const float* b_out      = (const float*)d_in[8];
    float* out = (float*)d_out;

    const int N = in_sizes[0] / IN_CH;   // 100000 (multiple of 16)
    const int E = in_sizes[2];           // 600000
    const int M = N * N_REL;             // 800000 (dst,type) keys

    // workspace layout (256 B aligned)
    char* w = (char*)d_ws;
    unsigned short* xb = (unsigned short*)w;   // [N,128] bf16, 25.6 MB
    w += (size_t)N * IN_CH * 2;
    unsigned short* wpk = (unsigned short*)w;  // 147,456 B
    w += (size_t)KSTEP * 4 * 64 * 8 * 2;
    int* cnt     = (int*)w;  w += (size_t)M * 4;
    int* off2    = (int*)w;  w += (size_t)(M + 1) * 4 + 252;
    int* cursor  = (int*)w;  w += (size_t)M * 4;
    int* bsum    = (int*)w;  w += 1024 * 4;
    unsigned int* csr = (unsigned int*)w;      // [E] u32, 2.4 MB

    const int total8 = N * IN_CH / 8;                  // 1.6M
    const int nb_xb  = (total8 + 255) / 256;           // 6250
    const int nb_z   = (M + 1023) / 1024;              // 782
    const int NB     = (M + SCAN_E - 1) / SCAN_E;      // 782 (<=1024)

    // 0) fused prep: x->bf16, pack Wcat, zero cnt
    prep_kernel<<<nb_xb + 36 + nb_z, 256, 0, stream>>>(
        x, xb, total8, W_rel, W_self, wpk, cnt, M, nb_xb);

    // 1) CSR build keyed by (dst, type)
    hist_kernel<<<(E + 255) / 256, 256, 0, stream>>>(edge_index, edge_type, cnt, E);
    scan_blocksum_kernel<<<NB, 256, 0, stream>>>(cnt, bsum, M);
    scan_partials_kernel<<<1, 256, 0, stream>>>(bsum, NB);
    scan_write_kernel<<<NB, 256, 0, stream>>>(cnt, bsum, off2, cursor, M);
    fill_csr_kernel<<<(E + 255) / 256, 256, 0, stream>>>(edge_index, edge_type,
                                                         cursor, csr, E);

    // 2) fused gather-sum + GEMM + relu + output projection
    rgcn_fused_kernel<<<N / 16, 1024, 0, stream>>>(
        (const unsigned int*)xb, wpk, off2, csr,
        b_rel, b_self, W_out, b_out, out, N);
}